// Round 1
// baseline (839.045 us; speedup 1.0000x reference)
//
#include <hip/hip_runtime.h>

typedef __attribute__((ext_vector_type(8))) short short8;
typedef __attribute__((ext_vector_type(4))) float f32x4;
typedef unsigned short u16;
typedef unsigned int u32;

#define MFMA16(a, b, c) __builtin_amdgcn_mfma_f32_16x16x32_bf16((a), (b), (c), 0, 0, 0)
#define SCALE_Q 0.1767766952966369f

__device__ __forceinline__ u16 f2bf(float x) {
  u32 u = __float_as_uint(x);
  u32 r = u + 0x7FFF + ((u >> 16) & 1);
  return (u16)(r >> 16);
}

// stage 128 rows x 128 bf16 cols into LDS (row stride 256B) with XOR swizzle
__device__ __forceinline__ void stage128(u16* lds, const u16* __restrict__ g, int stride, int tid) {
#pragma unroll
  for (int it = 0; it < 8; ++it) {
    int i = it * 256 + tid;
    int row = i >> 4, slot = i & 15;
    short8 v = *(const short8*)(g + row * stride + slot * 8);
    int byte_ = ((row << 8) + (slot << 4)) ^ ((row & 7) << 4);
    *(short8*)((char*)lds + byte_) = v;
  }
}

// fragment load from swizzled LDS tile (row stride 256B)
__device__ __forceinline__ short8 fld256(const u16* lds, int row, int kb) {
  int byte_ = ((row << 8) + kb) ^ ((row & 7) << 4);
  return *(const short8*)((const char*)lds + byte_);
}

__device__ __forceinline__ float gelu_f(float x) {
  float u = 0.7978845608f * (x + 0.044715f * x * x * x);
  float e = __expf(2.f * u);
  float t = 1.f - 2.f / (e + 1.f);
  return 0.5f * x * (1.f + t);
}

// ---------------- K0a: weight transpose + bf16 cast ----------------
__global__ __launch_bounds__(256) void k0_weights(
    const float* __restrict__ wq, const float* __restrict__ wk, const float* __restrict__ wv,
    const float* __restrict__ wo, const float* __restrict__ w1, const float* __restrict__ w2,
    const float* __restrict__ bq, const float* __restrict__ bk, const float* __restrict__ bv,
    u16* __restrict__ wqkvt, u16* __restrict__ wot, u16* __restrict__ w1t, u16* __restrict__ w2t,
    float* __restrict__ bqkv) {
  int idx = blockIdx.x * 256 + threadIdx.x;
  if (idx < 49152) {                       // wqkvt[384][128] = W^T, q cols pre-scaled
    int n = idx >> 7, k = idx & 127;
    float v;
    if (n < 128) v = wq[k * 128 + n] * SCALE_Q;
    else if (n < 256) v = wk[k * 128 + (n - 128)];
    else v = wv[k * 128 + (n - 256)];
    wqkvt[idx] = f2bf(v);
  } else if (idx < 65536) {                // wot[128][128]
    int j = idx - 49152;
    int n = j >> 7, k = j & 127;
    wot[j] = f2bf(wo[k * 128 + n]);
  } else if (idx < 131072) {               // w1t[512][128]
    int j = idx - 65536;
    int n = j >> 7, k = j & 127;
    w1t[j] = f2bf(w1[k * 512 + n]);
  } else if (idx < 196608) {               // w2t[128][512]
    int j = idx - 131072;
    int n = j >> 9, k = j & 511;
    w2t[j] = f2bf(w2[k * 128 + n]);
  } else if (idx < 196992) {               // bqkv[384]
    int n = idx - 196608;
    float v;
    if (n < 128) v = bq[n] * SCALE_Q;
    else if (n < 256) v = bk[n - 128];
    else v = bv[n - 256];
    bqkv[n] = v;
  }
}

// ---------------- K0b: bias+mask table in MFMA C-fragment layout ----------------
// layout: [wi 64][h 4][mt 4][nt 4][lane 64][reg 4] f32
__global__ __launch_bounds__(256) void k0_biasmask(const float* __restrict__ rel, float* __restrict__ bm) {
  int idx = blockIdx.x * 256 + threadIdx.x;   // 0 .. 1048575
  int reg = idx & 3;
  int lane = (idx >> 2) & 63;
  int nt = (idx >> 8) & 3;
  int mt = (idx >> 10) & 3;
  int h = (idx >> 12) & 3;
  int wi = idx >> 14;
  int r = mt * 16 + ((lane >> 4) << 2) + reg;  // query token in window
  int c = nt * 16 + (lane & 15);               // key token
  float v = -1e30f;
  if (r < 49 && c < 49) {
    int qr = r / 7, qc = r % 7, kr = c / 7, kc = c % 7;
    // reference: rel[q][k] = coords[k] - coords[q]
    int i0 = (kr - qr + 13) % 13, i1 = (kc - qc + 13) % 13;
    v = rel[(i0 * 13 + i1) * 4 + h];
    int gh = (wi >> 3) * 7 + qr, gw = (wi & 7) * 7 + qc;
    int kh = (wi >> 3) * 7 + kr, kw = (wi & 7) * 7 + kc;
    int rq = (gh < 49 ? 0 : (gh < 53 ? 1 : 2)) * 3 + (gw < 49 ? 0 : (gw < 53 ? 1 : 2));
    int rk = (kh < 49 ? 0 : (kh < 53 ? 1 : 2)) * 3 + (kw < 49 ? 0 : (kw < 53 ? 1 : 2));
    if (rq != rk) v -= 100.f;
  }
  bm[idx] = v;
}

// ---------------- K1: LN1 + roll(-3,-3) + window partition -> bf16 ----------------
__global__ __launch_bounds__(256) void k1_ln1(const float* __restrict__ x, const float* __restrict__ g,
                                              const float* __restrict__ b, u16* __restrict__ hwin) {
  int wid = threadIdx.x >> 6, lane = threadIdx.x & 63;
  int t = blockIdx.x * 4 + wid;                  // natural token b*3136 + oh*56 + ow
  float2 v = *(const float2*)(x + t * 128 + lane * 2);
  float s = v.x + v.y;
#pragma unroll
  for (int o = 1; o < 64; o <<= 1) s += __shfl_xor(s, o);
  float mu = s * 0.0078125f;
  float dx = v.x - mu, dy = v.y - mu;
  float q = dx * dx + dy * dy;
#pragma unroll
  for (int o = 1; o < 64; o <<= 1) q += __shfl_xor(q, o);
  float rstd = rsqrtf(q * 0.0078125f + 1e-5f);
  float y0 = dx * rstd * g[lane * 2] + b[lane * 2];
  float y1 = dy * rstd * g[lane * 2 + 1] + b[lane * 2 + 1];
  int bi = t / 3136, hw = t - bi * 3136;
  int oh = hw / 56, ow = hw - oh * 56;
  int gh = oh - 3; if (gh < 0) gh += 56;         // rolled coords
  int gw = ow - 3; if (gw < 0) gw += 56;
  int win = bi * 64 + (gh / 7) * 8 + gw / 7;
  int n = (gh % 7) * 7 + (gw % 7);
  u32 packed = (u32)f2bf(y0) | ((u32)f2bf(y1) << 16);
  *(u32*)(hwin + (win * 49 + n) * 128 + lane * 2) = packed;
}

// ---------------- K2: QKV GEMM (M=200704, K=128, N=384) ----------------
__global__ __launch_bounds__(256) void k2_qkv(const u16* __restrict__ hwin, const u16* __restrict__ wt,
                                              const float* __restrict__ bqkv, u16* __restrict__ qb,
                                              u16* __restrict__ kb, u16* __restrict__ vt) {
  __shared__ u16 lA[128 * 128];
  __shared__ u16 lB[128 * 128];
  int tid = threadIdx.x, mb = blockIdx.x, nb = blockIdx.y;
  stage128(lA, hwin + mb * 128 * 128, 128, tid);
  stage128(lB, wt + nb * 128 * 128, 128, tid);
  __syncthreads();
  int lane = tid & 63, w = tid >> 6;
  int wr = (w >> 1) * 64, wc = (w & 1) * 64;
  int g = lane >> 4, l15 = lane & 15;
  const f32x4 vz = {0.f, 0.f, 0.f, 0.f};
  f32x4 acc[4][4];
#pragma unroll
  for (int i = 0; i < 4; ++i)
#pragma unroll
    for (int j = 0; j < 4; ++j) acc[i][j] = vz;
#pragma unroll
  for (int kt = 0; kt < 4; ++kt) {
    short8 a[4], bfr[4];
#pragma unroll
    for (int mt = 0; mt < 4; ++mt) a[mt] = fld256(lA, wr + mt * 16 + l15, kt * 64 + g * 16);
#pragma unroll
    for (int nt = 0; nt < 4; ++nt) bfr[nt] = fld256(lB, wc + nt * 16 + l15, kt * 64 + g * 16);
#pragma unroll
    for (int mt = 0; mt < 4; ++mt)
#pragma unroll
      for (int nt = 0; nt < 4; ++nt) acc[mt][nt] = MFMA16(a[mt], bfr[nt], acc[mt][nt]);
  }
#pragma unroll
  for (int mt = 0; mt < 4; ++mt)
#pragma unroll
    for (int nt = 0; nt < 4; ++nt) {
      int ng = nb * 128 + wc + nt * 16 + l15;
      float bias = bqkv[ng];
#pragma unroll
      for (int reg = 0; reg < 4; ++reg) {
        int token = mb * 128 + wr + mt * 16 + g * 4 + reg;
        u16 hv = f2bf(acc[mt][nt][reg] + bias);
        if (nb == 0) qb[token * 128 + ng] = hv;
        else if (nb == 1) kb[token * 128 + ng - 128] = hv;
        else {
          int c = ng - 256;
          int win = token / 49, nn = token - win * 49;
          vt[win * 8192 + c * 64 + nn] = hv;   // V transposed, token-padded to 64
        }
      }
    }
}

// ---------------- K3: windowed attention, one wave per (window, head) ----------------
__global__ __launch_bounds__(256) void k3_attn(const u16* __restrict__ qb, const u16* __restrict__ kb,
                                               const u16* __restrict__ vt, const float* __restrict__ bm,
                                               u16* __restrict__ ao) {
  __shared__ u16 pl[4 * 4096];
  int win = blockIdx.x;
  int lane = threadIdx.x & 63, head = threadIdx.x >> 6;
  int g = lane >> 4, l15 = lane & 15;
  u16* myp = pl + head * 4096;
  short8 aq[4], bk_[4];
#pragma unroll
  for (int mt = 0; mt < 4; ++mt)
    aq[mt] = *(const short8*)(qb + (win * 49 + mt * 16 + l15) * 128 + head * 32 + g * 8);
#pragma unroll
  for (int nt = 0; nt < 4; ++nt)
    bk_[nt] = *(const short8*)(kb + (win * 49 + nt * 16 + l15) * 128 + head * 32 + g * 8);
  // S init = bias + mask (C-operand), then QK^T accumulates (q pre-scaled by 1/sqrt(32))
  const f32x4* bmv = (const f32x4*)bm + ((win & 63) * 4 + head) * 1024;
  f32x4 s[4][4];
#pragma unroll
  for (int mt = 0; mt < 4; ++mt)
#pragma unroll
    for (int nt = 0; nt < 4; ++nt) s[mt][nt] = bmv[(mt * 4 + nt) * 64 + lane];
#pragma unroll
  for (int mt = 0; mt < 4; ++mt)
#pragma unroll
    for (int nt = 0; nt < 4; ++nt) s[mt][nt] = MFMA16(aq[mt], bk_[nt], s[mt][nt]);
  // softmax per row (row lives in 16 lanes sharing g; cols = l15 + 16*nt)
#pragma unroll
  for (int mt = 0; mt < 4; ++mt)
#pragma unroll
    for (int reg = 0; reg < 4; ++reg) {
      float m = fmaxf(fmaxf(s[mt][0][reg], s[mt][1][reg]), fmaxf(s[mt][2][reg], s[mt][3][reg]));
#pragma unroll
      for (int o = 1; o < 16; o <<= 1) m = fmaxf(m, __shfl_xor(m, o));
      float p0 = __expf(s[mt][0][reg] - m);
      float p1 = __expf(s[mt][1][reg] - m);
      float p2 = __expf(s[mt][2][reg] - m);
      float p3 = __expf(s[mt][3][reg] - m);
      float sum = p0 + p1 + p2 + p3;
#pragma unroll
      for (int o = 1; o < 16; o <<= 1) sum += __shfl_xor(sum, o);
      float rinv = 1.f / sum;
      s[mt][0][reg] = p0 * rinv; s[mt][1][reg] = p1 * rinv;
      s[mt][2][reg] = p2 * rinv; s[mt][3][reg] = p3 * rinv;
    }
  // P -> LDS (bf16, row stride 128B, XOR swizzle)
#pragma unroll
  for (int mt = 0; mt < 4; ++mt)
#pragma unroll
    for (int nt = 0; nt < 4; ++nt)
#pragma unroll
      for (int reg = 0; reg < 4; ++reg) {
        int r = mt * 16 + g * 4 + reg, c = nt * 16 + l15;
        int byte_ = ((r << 7) + (c << 1)) ^ ((r & 7) << 4);
        *(u16*)((char*)myp + byte_) = f2bf(s[mt][nt][reg]);
      }
  __syncthreads();
  // PV: A = P rows (from LDS), B = V via vt (contiguous 16B)
  short8 vb[2][2];
#pragma unroll
  for (int kk = 0; kk < 2; ++kk)
#pragma unroll
    for (int n2 = 0; n2 < 2; ++n2)
      vb[kk][n2] = *(const short8*)(vt + win * 8192 + (head * 32 + n2 * 16 + l15) * 64 + kk * 32 + g * 8);
  const f32x4 vz = {0.f, 0.f, 0.f, 0.f};
  f32x4 o[4][2];
#pragma unroll
  for (int mt = 0; mt < 4; ++mt) { o[mt][0] = vz; o[mt][1] = vz; }
#pragma unroll
  for (int mt = 0; mt < 4; ++mt)
#pragma unroll
    for (int kk = 0; kk < 2; ++kk) {
      int r = mt * 16 + l15;
      int byte_ = ((r << 7) + kk * 64 + g * 16) ^ ((r & 7) << 4);
      short8 pa = *(const short8*)((const char*)myp + byte_);
#pragma unroll
      for (int n2 = 0; n2 < 2; ++n2) o[mt][n2] = MFMA16(pa, vb[kk][n2], o[mt][n2]);
    }
#pragma unroll
  for (int mt = 0; mt < 4; ++mt)
#pragma unroll
    for (int n2 = 0; n2 < 2; ++n2)
#pragma unroll
      for (int reg = 0; reg < 4; ++reg) {
        int r = mt * 16 + g * 4 + reg;
        if (r < 49) ao[(win * 49 + r) * 128 + head * 32 + n2 * 16 + l15] = f2bf(o[mt][n2][reg]);
      }
}

// ---------------- K4: proj GEMM + bias + residual -> h (d_out) + LN2 -> bf16 ----------------
__global__ __launch_bounds__(256) void k4_proj(const u16* __restrict__ ao, const u16* __restrict__ wot,
                                               const float* __restrict__ bo, const float* __restrict__ x,
                                               const float* __restrict__ g2, const float* __restrict__ b2,
                                               float* __restrict__ dout, u16* __restrict__ ln2) {
  __shared__ u16 lA[128 * 128];
  __shared__ u16 lB[128 * 128];
  int tid = threadIdx.x, mb = blockIdx.x;
  stage128(lA, ao + mb * 128 * 128, 128, tid);
  stage128(lB, wot, 128, tid);
  __syncthreads();
  int lane = tid & 63, w = tid >> 6, g = lane >> 4, l15 = lane & 15;
  const f32x4 vz = {0.f, 0.f, 0.f, 0.f};
  f32x4 acc[2][8];
#pragma unroll
  for (int i = 0; i < 2; ++i)
#pragma unroll
    for (int j = 0; j < 8; ++j) acc[i][j] = vz;
#pragma unroll
  for (int kt = 0; kt < 4; ++kt) {
    short8 a[2], bfr[8];
#pragma unroll
    for (int mt = 0; mt < 2; ++mt) a[mt] = fld256(lA, w * 32 + mt * 16 + l15, kt * 64 + g * 16);
#pragma unroll
    for (int nt = 0; nt < 8; ++nt) bfr[nt] = fld256(lB, nt * 16 + l15, kt * 64 + g * 16);
#pragma unroll
    for (int mt = 0; mt < 2; ++mt)
#pragma unroll
      for (int nt = 0; nt < 8; ++nt) acc[mt][nt] = MFMA16(a[mt], bfr[nt], acc[mt][nt]);
  }
#pragma unroll
  for (int mt = 0; mt < 2; ++mt)
#pragma unroll
    for (int reg = 0; reg < 4; ++reg) {
      int token = mb * 128 + w * 32 + mt * 16 + g * 4 + reg;
      float hv[8];
      float s1 = 0.f, s2 = 0.f;
#pragma unroll
      for (int nt = 0; nt < 8; ++nt) {
        int c = nt * 16 + l15;
        float v = acc[mt][nt][reg] + bo[c] + x[token * 128 + c];
        dout[token * 128 + c] = v;
        hv[nt] = v; s1 += v; s2 += v * v;
      }
#pragma unroll
      for (int o = 1; o < 16; o <<= 1) { s1 += __shfl_xor(s1, o); s2 += __shfl_xor(s2, o); }
      float mu = s1 * 0.0078125f;
      float rstd = rsqrtf(fmaxf(s2 * 0.0078125f - mu * mu, 0.f) + 1e-5f);
#pragma unroll
      for (int nt = 0; nt < 8; ++nt) {
        int c = nt * 16 + l15;
        ln2[token * 128 + c] = f2bf((hv[nt] - mu) * rstd * g2[c] + b2[c]);
      }
    }
}

// ---------------- K5: MLP GEMM1 + gelu (M=200704, K=128, N=512) ----------------
__global__ __launch_bounds__(256) void k5_mlp1(const u16* __restrict__ ln2, const u16* __restrict__ w1t,
                                               const float* __restrict__ b1, u16* __restrict__ g1) {
  __shared__ u16 lA[128 * 128];
  __shared__ u16 lB[128 * 128];
  int tid = threadIdx.x, mb = blockIdx.x, nb = blockIdx.y;
  stage128(lA, ln2 + mb * 128 * 128, 128, tid);
  stage128(lB, w1t + nb * 128 * 128, 128, tid);
  __syncthreads();
  int lane = tid & 63, w = tid >> 6;
  int wr = (w >> 1) * 64, wc = (w & 1) * 64;
  int g = lane >> 4, l15 = lane & 15;
  const f32x4 vz = {0.f, 0.f, 0.f, 0.f};
  f32x4 acc[4][4];
#pragma unroll
  for (int i = 0; i < 4; ++i)
#pragma unroll
    for (int j = 0; j < 4; ++j) acc[i][j] = vz;
#pragma unroll
  for (int kt = 0; kt < 4; ++kt) {
    short8 a[4], bfr[4];
#pragma unroll
    for (int mt = 0; mt < 4; ++mt) a[mt] = fld256(lA, wr + mt * 16 + l15, kt * 64 + g * 16);
#pragma unroll
    for (int nt = 0; nt < 4; ++nt) bfr[nt] = fld256(lB, wc + nt * 16 + l15, kt * 64 + g * 16);
#pragma unroll
    for (int mt = 0; mt < 4; ++mt)
#pragma unroll
      for (int nt = 0; nt < 4; ++nt) acc[mt][nt] = MFMA16(a[mt], bfr[nt], acc[mt][nt]);
  }
#pragma unroll
  for (int mt = 0; mt < 4; ++mt)
#pragma unroll
    for (int nt = 0; nt < 4; ++nt) {
      int ng = nb * 128 + wc + nt * 16 + l15;
      float bias = b1[ng];
#pragma unroll
      for (int reg = 0; reg < 4; ++reg) {
        int token = mb * 128 + wr + mt * 16 + g * 4 + reg;
        g1[token * 512 + ng] = f2bf(gelu_f(acc[mt][nt][reg] + bias));
      }
    }
}

// ---------------- K6: MLP GEMM2 + bias + residual (K=512, N=128) ----------------
__global__ __launch_bounds__(256) void k6_mlp2(const u16* __restrict__ g1, const u16* __restrict__ w2t,
                                               const float* __restrict__ b2, float* __restrict__ dout) {
  __shared__ u16 lA[128 * 128];
  __shared__ u16 lB[128 * 128];
  int tid = threadIdx.x, mb = blockIdx.x;
  int lane = tid & 63, w = tid >> 6;
  int wr = (w >> 1) * 64, wc = (w & 1) * 64;
  int g = lane >> 4, l15 = lane & 15;
  const f32x4 vz = {0.f, 0.f, 0.f, 0.f};
  f32x4 acc[4][4];
#pragma unroll
  for (int i = 0; i < 4; ++i)
#pragma unroll
    for (int j = 0; j < 4; ++j) acc[i][j] = vz;
  for (int kc = 0; kc < 4; ++kc) {
    if (kc) __syncthreads();
    stage128(lA, g1 + mb * (128 * 512) + kc * 128, 512, tid);
    stage128(lB, w2t + kc * 128, 512, tid);
    __syncthreads();
#pragma unroll
    for (int kt = 0; kt < 4; ++kt) {
      short8 a[4], bfr[4];
#pragma unroll
      for (int mt = 0; mt < 4; ++mt) a[mt] = fld256(lA, wr + mt * 16 + l15, kt * 64 + g * 16);
#pragma unroll
      for (int nt = 0; nt < 4; ++nt) bfr[nt] = fld256(lB, wc + nt * 16 + l15, kt * 64 + g * 16);
#pragma unroll
      for (int mt = 0; mt < 4; ++mt)
#pragma unroll
        for (int nt = 0; nt < 4; ++nt) acc[mt][nt] = MFMA16(a[mt], bfr[nt], acc[mt][nt]);
    }
  }
#pragma unroll
  for (int mt = 0; mt < 4; ++mt)
#pragma unroll
    for (int nt = 0; nt < 4; ++nt) {
      int ng = wc + nt * 16 + l15;
      float bias = b2[ng];
#pragma unroll
      for (int reg = 0; reg < 4; ++reg) {
        int token = mb * 128 + wr + mt * 16 + g * 4 + reg;
        int i = token * 128 + ng;
        dout[i] = acc[mt][nt][reg] + bias + dout[i];
      }
    }
}

extern "C" void kernel_launch(void* const* d_in, const int* in_sizes, int n_in,
                              void* d_out, int out_size, void* d_ws, size_t ws_size,
                              hipStream_t stream) {
  const float* x    = (const float*)d_in[0];
  const float* wq   = (const float*)d_in[1];
  const float* bq   = (const float*)d_in[2];
  const float* wk   = (const float*)d_in[3];
  const float* bk   = (const float*)d_in[4];
  const float* wv   = (const float*)d_in[5];
  const float* bv   = (const float*)d_in[6];
  const float* wo   = (const float*)d_in[7];
  const float* bo   = (const float*)d_in[8];
  const float* rel  = (const float*)d_in[9];
  const float* ln1g = (const float*)d_in[10];
  const float* ln1b = (const float*)d_in[11];
  const float* ln2g = (const float*)d_in[12];
  const float* ln2b = (const float*)d_in[13];
  const float* w1   = (const float*)d_in[14];
  const float* b1   = (const float*)d_in[15];
  const float* w2   = (const float*)d_in[16];
  const float* b2   = (const float*)d_in[17];
  float* out = (float*)d_out;
  char* ws = (char*)d_ws;

  const size_t TOK = 200704;          // B * H * W
  float* bmask = (float*)(ws);                                   // 4 MB
  u16* wqkvt = (u16*)(ws + (size_t)(4 << 20));                   // 192 KB
  u16* wot   = (u16*)(ws + (size_t)(4 << 20) + 196608);          // 32 KB
  u16* w1t   = (u16*)(ws + (size_t)(4 << 20) + 229376);          // 128 KB
  u16* w2t   = (u16*)(ws + (size_t)(4 << 20) + 360448);          // 128 KB
  float* bqkv = (float*)(ws + (size_t)(4 << 20) + 491520);       // 1.5 KB
  const size_t SB = TOK * 128 * 2;    // 51,380,224 bytes per bf16 [TOK][128] buffer
  u16* hwin = (u16*)(ws + (size_t)(8 << 20));
  u16* qb   = (u16*)(ws + (size_t)(8 << 20) + SB);
  u16* kb   = (u16*)(ws + (size_t)(8 << 20) + 2 * SB);
  u16* vt   = (u16*)(ws + (size_t)(8 << 20) + 3 * SB);           // 64 MB, [4096][128][64]
  u16* attn = hwin;   // reuse (hwin dead after K2)
  u16* ln2  = qb;     // reuse (q dead after K3)
  u16* g1b  = kb;     // reuse (k, vt dead after K3): 196 MB spanning kb/vt/beyond

  k0_weights<<<770, 256, 0, stream>>>(wq, wk, wv, wo, w1, w2, bq, bk, bv,
                                      wqkvt, wot, w1t, w2t, bqkv);
  k0_biasmask<<<4096, 256, 0, stream>>>(rel, bmask);
  k1_ln1<<<50176, 256, 0, stream>>>(x, ln1g, ln1b, hwin);
  k2_qkv<<<dim3(1568, 3), dim3(256), 0, stream>>>(hwin, wqkvt, bqkv, qb, kb, vt);
  k3_attn<<<4096, 256, 0, stream>>>(qb, kb, vt, bmask, attn);
  k4_proj<<<1568, 256, 0, stream>>>(attn, wot, bo, x, ln2g, ln2b, out, ln2);
  k5_mlp1<<<dim3(1568, 4), dim3(256), 0, stream>>>(ln2, w1t, b1, g1b);
  k6_mlp2<<<1568, 256, 0, stream>>>(g1b, w2t, b2, out);
}